// Round 8
// baseline (213.002 us; speedup 1.0000x reference)
//
#include <hip/hip_runtime.h>

// CfC dose controller: B=4096 sequences, T=512 sequential steps.
// Layers (fan_in, hid): (4,9) (9,6) (6,1); gates ff1, ff2, t (t = ta+tb folded).
// f-space: gate value f = 1/(1 + 2^y), y pre-scaled dot
//   ff gates: y = -2*log2e*a  -> tanh(a) = 2f-1
//   t  gate : y = -  log2e*a  -> sigma(a) = f
// h_true = 2F-1 folded into consumer weights+biases.
//
// R8 = R7 math verbatim + lean steady-state codegen:
//   - FAST path (steady, all roles on): UNCONDITIONAL LDS writes; non-owner
//     lanes write to unique per-lane dump slots (no exec-mask save/restore).
//   - x prefetch via incrementing pointer; last 2 steady iters peeled so no
//     per-iter clamp/64-bit address recompute.
//   - SLOW path (R7-style predicated writes) for prologue/epilogue partial
//     steps so disabled roles can't corrupt state.
//   - LDS region per element: 128 floats. 0..15 state [F0 x9|F1 x6|F2],
//     32..63 sigma ring, 64..95 dump. Ring flushed every 32 steps as one
//     coalesced 32-lane store.
//   - Skew: iter i = L0(i) | L1(i-1) | L2(i-2) | SIG(i-3); membar() between
//     LDS writes and state reads (TBAA fix, R6-verified).

#define LOG2E 1.44269504088896340736f
#define SMIN  0.001f

static constexpr int BATCH = 4096;
static constexpr int TLEN  = 512;

__device__ __forceinline__ float frcp(float x)  { return __builtin_amdgcn_rcpf(x); }
__device__ __forceinline__ float fexp2(float x) { return __builtin_amdgcn_exp2f(x); }
__device__ __forceinline__ void membar() { asm volatile("" ::: "memory"); }
// DPP: 0x39 quad_perm[1,2,3,0]; 0x4E quad_perm[2,3,0,1]; 0x104 row_shl:4; 0x108 row_shl:8
template<int CTRL>
__device__ __forceinline__ float dppf(float v) {
    return __int_as_float(__builtin_amdgcn_update_dpp(
        0, __float_as_int(v), CTRL, 0xF, 0xF, true));
}

struct Params { const float* p[29]; float* out; };

__global__ __launch_bounds__(256, 2) void cfc_kernel(Params P) {
    const int tid  = threadIdx.x;
    const int lih  = tid & 31;                       // lane within half-wave
    const int half = ((blockIdx.x << 8) + tid) >> 5; // batch element 0..4095
    const int q    = lih >> 2;                       // quad index
    const int s    = lih & 3;                        // slot within quad
    const bool is3  = (lih == 3);                    // L0 neuron-8 f1 holder
    const bool is28 = (lih == 28);                   // SIG lane

    __shared__ float lds[8 * 128];                   // 8 halves x 128 floats
    float* hp = &lds[(tid >> 5) << 7];

    // layout: 0..15 state, 32..63 sigma ring, 64..95 per-lane dump
    const int  dump = 64 + lih;
    const bool ownA = (s == 0 && q < 8) || is3;
    const int  slA  = ownA ? (is3 ? 8 : q) : dump;   // static write addr (A)
    const bool ownB1 = (s == 0 && q < 6);
    const bool ownB2 = (lih == 24);
    const int  slB   = ownB1 ? (9 + q) : (ownB2 ? 15 : dump);

    // ---------------- weights: A (layer 0) ----------------------------------
    float wA[13]; float bA = 0.f;
    {
        const float *Wf1 = P.p[1], *Bf1 = P.p[2], *Wf2 = P.p[3], *Bf2 = P.p[4];
        const float *Wa  = P.p[5], *Ba  = P.p[6], *Wb  = P.p[7], *Bb  = P.p[8];
        const float *M   = P.p[9];
        const int  j   = (s == 3) ? 8 : q;
        const int  g   = (s == 3) ? q : s;
        const bool act = (s == 3) ? (q < 3) : (q < 8);
        const float sc = (g == 2) ? -LOG2E : -2.0f * LOG2E;
        float bias = 0.f;
        if (act) bias = sc * ((g == 0) ? Bf1[j] : (g == 1) ? Bf2[j] : (Ba[j] + Bb[j]));
        #pragma unroll
        for (int k = 0; k < 13; ++k) {
            float c = 0.f;
            if (act) {
                const int idx = j * 13 + k;
                const float wv = (g == 0) ? Wf1[idx] * M[idx]
                               : (g == 1) ? Wf2[idx] * M[idx]
                               : (Wa[idx] + Wb[idx]);   // time gates dense
                c = sc * wv;
            }
            if (k < 4) wA[k] = c;
            else       { wA[k] = c + c; bias -= c; }    // f-col: 2c*F + (b-c)
        }
        bA = bias;
    }
    // ---------------- weights: B (merged L1 | L2 | SIG) ----------------------
    float wB[16]; float bB = 0.f;
    #pragma unroll
    for (int k = 0; k < 16; ++k) wB[k] = 0.f;
    if (q < 6 && s < 3) {            // role L1: neuron j=q, gate g=s
        const float *Wf1 = P.p[10], *Bf1 = P.p[11], *Wf2 = P.p[12], *Bf2 = P.p[13];
        const float *Wa  = P.p[14], *Ba  = P.p[15], *Wb  = P.p[16], *Bb  = P.p[17];
        const float *M   = P.p[18];
        const int j = q, g = s;
        const float sc = (g == 2) ? -LOG2E : -2.0f * LOG2E;
        float bias = sc * ((g == 0) ? Bf1[j] : (g == 1) ? Bf2[j] : (Ba[j] + Bb[j]));
        #pragma unroll
        for (int k = 0; k < 15; ++k) {
            const int idx = j * 15 + k;
            const float wv = (g == 0) ? Wf1[idx] * M[idx]
                           : (g == 1) ? Wf2[idx] * M[idx]
                           : (Wa[idx] + Wb[idx]);
            const float c = sc * wv;
            wB[k] = c + c; bias -= c;
        }
        bB = bias;
    } else if (lih >= 24 && lih < 27) {  // role L2: gate g=lih-24
        const float *Wf1 = P.p[19], *Bf1 = P.p[20], *Wf2 = P.p[21], *Bf2 = P.p[22];
        const float *Wa  = P.p[23], *Ba  = P.p[24], *Wb  = P.p[25], *Bb  = P.p[26];
        const float *M   = P.p[27];
        const int g = lih - 24;
        const float sc = (g == 2) ? -LOG2E : -2.0f * LOG2E;
        float bias = sc * ((g == 0) ? Bf1[0] : (g == 1) ? Bf2[0] : (Ba[0] + Bb[0]));
        #pragma unroll
        for (int k = 0; k < 7; ++k) {
            const float wv = (g == 0) ? Wf1[k] * M[k]
                           : (g == 1) ? Wf2[k] * M[k]
                           : (Wa[k] + Wb[k]);
            const float c = sc * wv;
            const int pos = (k < 6) ? (9 + k) : 15;
            wB[pos] = c + c; bias -= c;
        }
        bB = bias;
    } else if (is28) {                   // role SIG: f = sigmoid(2*F2 - 1)
        wB[15] = -2.0f * LOG2E;
        bB = LOG2E;
    }

    const float sig_scale = P.p[28][0];

    // ---------------- init state board (f-space; h=0 <=> F=0.5) -------------
    if (lih < 16) hp[lih] = 0.5f;
    membar();

    float4 r0 = *(const float4*)(hp + 0);    // F0[0..3]
    float4 r1 = *(const float4*)(hp + 4);    // F0[4..7]
    float4 r2 = *(const float4*)(hp + 8);    // F0[8], F1[0..2]
    float4 r3 = *(const float4*)(hp + 12);   // F1[3..5], F2

    const float4* xp = reinterpret_cast<const float4*>(P.p[0]) + (size_t)half * TLEN;
    float* sigp = P.out + (size_t)half * TLEN + lih;

    // ---- dot helpers (consume current state regs) --------------------------
    auto dotA = [&](const float4 xv) {
        float a = fmaf(wA[0],  xv.x, bA);   float b = wA[1] * xv.y;
        a = fmaf(wA[2],  xv.z, a);  b = fmaf(wA[3],  xv.w, b);
        a = fmaf(wA[4],  r0.x, a);  b = fmaf(wA[5],  r0.y, b);
        a = fmaf(wA[6],  r0.z, a);  b = fmaf(wA[7],  r0.w, b);
        a = fmaf(wA[8],  r1.x, a);  b = fmaf(wA[9],  r1.y, b);
        a = fmaf(wA[10], r1.z, a);  b = fmaf(wA[11], r1.w, b);
        a = fmaf(wA[12], r2.x, a);
        return a + b;
    };
    auto dotB = [&]() {
        float a = fmaf(wB[0],  r0.x, bB);   float b = wB[1] * r0.y;
        a = fmaf(wB[2],  r0.z, a);  b = fmaf(wB[3],  r0.w, b);
        a = fmaf(wB[4],  r1.x, a);  b = fmaf(wB[5],  r1.y, b);
        a = fmaf(wB[6],  r1.z, a);  b = fmaf(wB[7],  r1.w, b);
        a = fmaf(wB[8],  r2.x, a);  b = fmaf(wB[9],  r2.y, b);
        a = fmaf(wB[10], r2.z, a);  b = fmaf(wB[11], r2.w, b);
        a = fmaf(wB[12], r3.x, a);  b = fmaf(wB[13], r3.y, b);
        a = fmaf(wB[14], r3.z, a);  b = fmaf(wB[15], r3.w, b);
        return a + b;
    };
    auto combA = [&](float y) {
        const float f   = frcp(1.0f + fexp2(y));
        const float fq1 = dppf<0x39>(f);   // lane 4j <- 4j+1 (f2)
        const float fq2 = dppf<0x4E>(f);   // lane 4j <- 4j+2 (ft)
        const float fr1 = dppf<0x104>(f);  // lane 3  <- 7
        const float fr2 = dppf<0x108>(f);  // lane 3  <- 11
        const float f2v = is3 ? fr1 : fq1;
        const float ftv = is3 ? fr2 : fq2;
        return fmaf(ftv, f2v - f, f);
    };
    auto reload = [&]() {
        membar();                          // LDS write->read order (TBAA fix)
        r0 = *(const float4*)(hp + 0);
        r1 = *(const float4*)(hp + 4);
        r2 = *(const float4*)(hp + 8);
        r3 = *(const float4*)(hp + 12);
    };
    auto flush = [&](int tS) {
        if ((tS & 31) == 31) {             // wave-uniform scalar branch
            const float fr = hp[32 + lih];
            *sigp = fmaf(sig_scale, fr, SMIN);
            sigp += 32;
        }
    };

    // ---- FAST: steady-state step, all roles, branchless writes -------------
    auto FAST = [&](const float4 xv, int tS) {
        const float yA = dotA(xv);
        const float yB = dotB();
        const float FA = combA(yA);
        hp[slA] = FA;                      // unconditional; non-owners -> dump
        const float f   = frcp(1.0f + fexp2(yB));
        const float fq1 = dppf<0x39>(f);
        const float fq2 = dppf<0x4E>(f);
        const float FB  = fmaf(fq2, fq1 - f, f);
        const int   slot = is28 ? (32 + (tS & 31)) : slB;
        hp[slot] = is28 ? f : FB;          // unconditional; non-owners -> dump
        reload();
        flush(tS);
    };

    // ---- SLOW: predicated step for prologue/epilogue ------------------------
    auto SLOW = [&](const float4 xv, int tS, bool dA, bool dB1, bool dB2, bool dSG) {
        const bool doB = dB1 || dB2 || dSG;
        float yA = 0.f, yB = 0.f;
        if (dA)  yA = dotA(xv);
        if (doB) yB = dotB();
        if (dA) {
            const float FA = combA(yA);
            if (ownA) hp[ownA ? slA : 0] = FA;
        }
        if (doB) {
            const float f   = frcp(1.0f + fexp2(yB));
            const float fq1 = dppf<0x39>(f);
            const float fq2 = dppf<0x4E>(f);
            const float FB  = fmaf(fq2, fq1 - f, f);
            const float wsrc = is28 ? f : FB;
            const int   slot = is28 ? (32 + (tS & 31)) : slB;
            const bool  pred = (dB1 && ownB1) || (dB2 && ownB2) || (dSG && is28);
            if (pred) hp[slot] = wsrc;
        }
        reload();
        if (dSG) flush(tS);
    };

    // ---------------- prologue (fill 3-stage skew) ---------------------------
    SLOW(xp[0], 0, true, false, false, false);
    SLOW(xp[1], 0, true, true,  false, false);
    SLOW(xp[2], 0, true, true,  true,  false);

    // ---------------- steady: iters i=3..509 (tS=0..506), then 2 peeled ------
    float4 xv = xp[3], xn = xp[4];
    const float4* xq = xp + 5;
    for (int tS = 0; tS <= 506; ++tS) {
        FAST(xv, tS);
        xv = xn;
        xn = *xq++;                        // prefetch xp[tS+5] <= xp[511]
    }
    FAST(xv, 507); xv = xn;                // i=510
    FAST(xv, 508);                         // i=511

    // ---------------- epilogue (drain skew) ----------------------------------
    SLOW(xv, 509, false, true,  true,  true);   // L1(511), L2(510), sig(509)
    SLOW(xv, 510, false, false, true,  true);   // L2(511), sig(510)
    SLOW(xv, 511, false, false, false, true);   // sig(511)  (flush #16)

    // final states in slot order == output order: [F0 0..8 | F1 0..5 | F2]
    float hsel = r0.x;
    if (lih == 1)  hsel = r0.y;
    if (lih == 2)  hsel = r0.z;
    if (lih == 3)  hsel = r0.w;
    if (lih == 4)  hsel = r1.x;
    if (lih == 5)  hsel = r1.y;
    if (lih == 6)  hsel = r1.z;
    if (lih == 7)  hsel = r1.w;
    if (lih == 8)  hsel = r2.x;
    if (lih == 9)  hsel = r2.y;
    if (lih == 10) hsel = r2.z;
    if (lih == 11) hsel = r2.w;
    if (lih == 12) hsel = r3.x;
    if (lih == 13) hsel = r3.y;
    if (lih == 14) hsel = r3.z;
    if (lih == 15) hsel = r3.w;
    if (lih < 16) {
        float* hx = P.out + (size_t)BATCH * TLEN + (size_t)half * 16 + lih;
        *hx = fmaf(2.0f, hsel, -1.0f);
    }
}

extern "C" void kernel_launch(void* const* d_in, const int* in_sizes, int n_in,
                              void* d_out, int out_size, void* d_ws, size_t ws_size,
                              hipStream_t stream) {
    (void)in_sizes; (void)n_in; (void)out_size; (void)d_ws; (void)ws_size;
    Params P;
    for (int i = 0; i < 29; ++i) P.p[i] = (const float*)d_in[i];
    P.out = (float*)d_out;
    // 4096 batch elements, one per 32-lane half-wave: 512 blocks * 256 threads
    hipLaunchKernelGGL(cfc_kernel, dim3(BATCH / 8), dim3(256), 0, stream, P);
}